// Round 3
// baseline (253.943 us; speedup 1.0000x reference)
//
#include <hip/hip_runtime.h>

// kernel:  (N=8, K2=25, H=128, W=128) fp32
// low_fea: (N=8, C=256, H=128, W=128) fp32
// out[n,c,y,x] = low_fea[n,c,y,x] * S[n,y,x]
// S[n,y,x]  = sum_{a,b in [0,5)} kernel[n, a*5+b, y+2-a, x+2-b]  (0 outside bounds)
#define NN 8
#define CC 256
#define HH 128
#define WW 128
#define KK 5
#define PAD 2

// Single fused kernel, 2048 blocks x 256 threads:
//   bid -> (chunk = bid>>10, row = bid&1023). Two blocks per (n,y) row, each
//   handling 128 channels. 2048 blocks * 4 waves = 8192 waves = 100% of device
//   wave slots (vs 50% cap at 1024 blocks in round 1).
// S recomputed per block (2x redundancy, L2/L3-hit: kernel tensor is 13 MB).
// chunk in the HIGH bit => the two blocks sharing a row are bid and bid+1024;
// 1024 % 8 == 0 so they land on the same XCD -> 2nd block's taps are L2 hits.
__global__ __launch_bounds__(256) void fused_scale_kernel2(
    const float* __restrict__ kern,
    const float* __restrict__ low,
    float* __restrict__ out)
{
    __shared__ __align__(16) float S[WW];

    const int bid   = blockIdx.x;        // 0 .. 2047
    const int chunk = bid >> 10;         // 0 or 1 (channel half)
    const int row   = bid & 1023;        // n*128 + y
    const int n     = row >> 7;
    const int y     = row & (HH - 1);
    const int tid   = threadIdx.x;

    // --- Stage 1: S[x] for this (n, y) row (threads 0..127) ---------------
    if (tid < WW) {
        const int x = tid;
        float s = 0.0f;
        const float* kb = kern + (size_t)n * (KK * KK) * HH * WW;
#pragma unroll
        for (int a = 0; a < KK; ++a) {
            const int yy = y + PAD - a;
            if (yy >= 0 && yy < HH) {
#pragma unroll
                for (int b = 0; b < KK; ++b) {
                    const int xx = x + PAD - b;
                    if (xx >= 0 && xx < WW) {
                        s += kb[((size_t)(a * KK + b) * HH + yy) * WW + xx];
                    }
                }
            }
        }
        S[x] = s;
    }
    __syncthreads();

    // --- Stage 2: stream 128 channels of row (n, y) -----------------------
    // xq = float4 index within the row (W/4 = 32), loop-invariant per thread.
    const float4* lf4  = (const float4*)low;
    float4*       out4 = (float4*)out;
    const int    xq    = tid & 31;
    const float4 s4    = *(const float4*)&S[xq * 4];
    const size_t base4 = ((size_t)n * CC * HH + (size_t)y) * (WW / 4);
    const int    c0    = chunk * 128 + (tid >> 5);

#pragma unroll 4
    for (int it = 0; it < 16; ++it) {
        const int    c   = c0 + it * 8;
        const size_t idx = base4 + (size_t)c * (HH * WW / 4) + (size_t)xq;
        float4 v = lf4[idx];
        float4 r;
        r.x = v.x * s4.x;
        r.y = v.y * s4.y;
        r.z = v.z * s4.z;
        r.w = v.w * s4.w;
        out4[idx] = r;
    }
}

extern "C" void kernel_launch(void* const* d_in, const int* in_sizes, int n_in,
                              void* d_out, int out_size, void* d_ws, size_t ws_size,
                              hipStream_t stream) {
    const float* kern = (const float*)d_in[0];  // (8, 25, 128, 128)
    const float* low  = (const float*)d_in[1];  // (8, 256, 128, 128)
    float* out = (float*)d_out;                 // (8, 256, 128, 128)

    fused_scale_kernel2<<<dim3(2048), dim3(256), 0, stream>>>(kern, low, out);
}